// Round 8
// baseline (207.265 us; speedup 1.0000x reference)
//
#include <hip/hip_runtime.h>
#include <hip/hip_bf16.h>
#include <cstdint>
#include <cstddef>

static constexpr int Bk  = 4;
static constexpr int N1k = 2048;
static constexpr int N2k = 8192;
static constexpr int Ck  = 288;
static constexpr int NSk = 32;
static constexpr int TRB = (N2k / 32) * (Ck / 32) * Bk;   // 9216 transpose blocks

typedef __hip_bfloat16 bf16;

static __device__ __forceinline__ float bfu(unsigned short u) {
  return __uint_as_float((unsigned)u << 16);
}

// ---------------------------------------------------------------------------
// K0 (heterogeneous grid): blocks [0,TRB) transpose support_features
// [B,C,N2] fp32 -> Ftr [B,N2,C] bf16 (+ block 0 zeroes sums & counter);
// blocks [TRB, TRB+2048) run the masked ball query (wave per query,
// 4 pts/lane/iter with scalar prefetch). BQ overlaps the transpose stream.
// ---------------------------------------------------------------------------
__global__ __launch_bounds__(256) void k_pre(
    const float* __restrict__ F, const float* __restrict__ sxyz,
    const float* __restrict__ smask, const float* __restrict__ qxyz,
    const float* __restrict__ qmask, bf16* __restrict__ Ftr,
    int* __restrict__ idxArr, int* __restrict__ cntArr,
    float* __restrict__ sums, unsigned int* __restrict__ counter) {
  __shared__ float tile[32][33];
  int t = threadIdx.x;

  if (blockIdx.x < TRB) {
    // ---- transpose part ----
    int i  = blockIdx.x;
    int sT = (i & 255) * 32;
    int yz = i >> 8;
    int cT = (yz % 9) * 32;
    int b  = yz / 9;
    int tx = t & 31, ty = t >> 5;      // 32 x 8
    const float* Fb = F + (size_t)b * Ck * N2k;
    #pragma unroll
    for (int j = 0; j < 32; j += 8)
      tile[ty + j][tx] = Fb[(size_t)(cT + ty + j) * N2k + sT + tx];
    if (i == 0) {
      for (int k = t; k < 3 * Bk * Ck; k += 256) sums[k] = 0.f;
      if (t == 0) *counter = 0u;
    }
    __syncthreads();
    bf16* Ob = Ftr + (size_t)b * N2k * Ck;
    #pragma unroll
    for (int j = 0; j < 32; j += 8)
      Ob[(size_t)(sT + ty + j) * Ck + cT + tx] = __float2bfloat16(tile[tx][ty + j]);
    return;
  }

  // ---- ball query part ----
  int wave = (blockIdx.x - TRB) * 4 + (t >> 6);
  int lane = t & 63;
  int b = wave >> 11;                  // N1k = 2048
  int n = wave & (N1k - 1);
  int q = b * N1k + n;
  float qm = qmask[q];
  float qx = qxyz[q * 3 + 0];
  float qy = qxyz[q * 3 + 1];
  float qz = qxyz[q * 3 + 2];
  int cnt = 0, firstIdx = 0;
  int* myIdx = idxArr + (size_t)q * NSk;
  const float* Sx = sxyz + (size_t)b * N2k * 3;
  const float* Sm = smask + (size_t)b * N2k;
  if (qm > 0.f) {
    unsigned long long lmlt = (1ull << lane) - 1ull;
    float cx[4], cy[4], cz[4], cm[4];
    #pragma unroll
    for (int u = 0; u < 4; ++u) {
      int s = u * 64 + lane;
      cx[u] = Sx[3 * s]; cy[u] = Sx[3 * s + 1]; cz[u] = Sx[3 * s + 2];
      cm[u] = Sm[s];
    }
    for (int s0 = 0; s0 < N2k && cnt < NSk; s0 += 256) {
      float nx[4], ny[4], nz[4], nm[4];
      #pragma unroll
      for (int u = 0; u < 4; ++u) {
        int sp = s0 + 256 + u * 64 + lane;
        sp = (sp < N2k) ? sp : 0;      // clamped, unconditional prefetch
        nx[u] = Sx[3 * sp]; ny[u] = Sx[3 * sp + 1]; nz[u] = Sx[3 * sp + 2];
        nm[u] = Sm[sp];
      }
      #pragma unroll
      for (int u = 0; u < 4; ++u) {
        float dx = qx - cx[u], dy = qy - cy[u], dz = qz - cz[u];
        // match numpy association: (dx^2 + dy^2) + dz^2, no FMA contraction
        float d2 = __fadd_rn(__fadd_rn(__fmul_rn(dx, dx), __fmul_rn(dy, dy)),
                             __fmul_rn(dz, dz));
        bool valid = (d2 < 0.04f) && (cm[u] > 0.f);
        unsigned long long m = __ballot(valid);
        if (cnt == 0 && m != 0ull) firstIdx = s0 + u * 64 + (int)__builtin_ctzll(m);
        int p = cnt + (int)__popcll(m & lmlt);
        if (valid && p < NSk) myIdx[p] = s0 + u * 64 + lane;
        cnt += (int)__popcll(m);
      }
      #pragma unroll
      for (int u = 0; u < 4; ++u) {
        cx[u] = nx[u]; cy[u] = ny[u]; cz[u] = nz[u]; cm[u] = nm[u];
      }
    }
    if (cnt > NSk) cnt = NSk;
  }
  for (int p = cnt + lane; p < NSk; p += 64) myIdx[p] = firstIdx;
  if (lane == 0) cntArr[q] = cnt;
}

// ---------------------------------------------------------------------------
// K1: aggregation + tail excite. Block = 192 = 2 groups x 96; group handles
// one query per "it" (2 its -> 4 queries/block -> 2048 blocks). b = blockIdx&3
// pins XCDs to one batch's Ftr slice. Thread j<72 of a group owns channels
// [4j,4j+4) loaded as one ushort4 (8B).
// Algebra: a1 = sum_{k<cnt} F[idx_k][c]*rel_k[c%3] (masked sum);
//          a2 (unmasked, for gse) = a1 + (32-cnt')*c_first  (pads repeat
//          the firstIdx term); U = qm>0 ? a1/cnt : c_first.
// Per-(b,c) sums via LDS merge + atomics; LAST block (counter) computes the
// SE MLP + LN fold -> scaleA/biasB, replacing the separate k_excite kernel.
// ---------------------------------------------------------------------------
__global__ __launch_bounds__(192, 6) void k_aggregate(
    const bf16* __restrict__ Ftr, const float* __restrict__ qxyz,
    const float* __restrict__ sxyz, const float* __restrict__ qmask,
    const int* __restrict__ idxArr, const int* __restrict__ cntArr,
    bf16* __restrict__ U, float* __restrict__ sums,
    const float* __restrict__ w1, const float* __restrict__ w2,
    const float* __restrict__ gamma, const float* __restrict__ beta,
    float* __restrict__ scaleA, float* __restrict__ biasB,
    unsigned int* __restrict__ counter) {
  __shared__ int   sidx[2][NSk];
  __shared__ float srel[2][NSk][3];
  __shared__ int   scnt[2];
  __shared__ float sqm[2];
  __shared__ float red[3][Ck];
  __shared__ float xgse[Bk * Ck];
  __shared__ float xhid[Bk * 18];
  __shared__ int   isLast;

  int t = threadIdx.x;
  int b = blockIdx.x & 3;
  int nbase = (blockIdx.x >> 2) * 4;    // 512 blocks per batch, 4 queries each
  int g = t / 96;
  int j = t % 96;
  int a0 = j % 3, a1x = (a0 + 1) % 3, a2x = (a0 + 2) % 3;

  float accS2[4] = {0.f, 0.f, 0.f, 0.f};
  float accU[4]  = {0.f, 0.f, 0.f, 0.f};
  float accU2[4] = {0.f, 0.f, 0.f, 0.f};
  const bf16* Fb = Ftr + (size_t)b * N2k * Ck;

  for (int it = 0; it < 2; ++it) {
    int n = nbase + it * 2 + g;
    int q = b * N1k + n;
    __syncthreads();
    if (j < NSk) {
      int i = idxArr[(size_t)q * NSk + j];
      sidx[g][j] = i;
      float qx = qxyz[q * 3 + 0], qy = qxyz[q * 3 + 1], qz = qxyz[q * 3 + 2];
      srel[g][j][0] = (sxyz[(b * N2k + i) * 3 + 0] - qx) / 0.2f;
      srel[g][j][1] = (sxyz[(b * N2k + i) * 3 + 1] - qy) / 0.2f;
      srel[g][j][2] = (sxyz[(b * N2k + i) * 3 + 2] - qz) / 0.2f;
      if (j == 0) { scnt[g] = cntArr[q]; sqm[g] = qmask[q]; }
    }
    __syncthreads();

    int cnt  = scnt[g];
    float qmv = sqm[g];
    int kend = (qmv > 0.f) ? cnt : 0;          // pads contribute via cf
    float finv = (cnt > 0) ? (1.f / (float)cnt) : 0.f;

    if (j < 72) {
      float a1[4] = {0.f, 0.f, 0.f, 0.f};
      float cf[4] = {0.f, 0.f, 0.f, 0.f};
      #pragma unroll 8
      for (int k = 0; k < kend; ++k) {
        const ushort4* rowv =
            reinterpret_cast<const ushort4*>(Fb + (size_t)sidx[g][k] * Ck) + j;
        ushort4 v = *rowv;
        float r0 = srel[g][k][a0];
        float r1 = srel[g][k][a1x];
        float r2 = srel[g][k][a2x];
        float t0 = bfu(v.x) * r0;
        float t1 = bfu(v.y) * r1;
        float t2 = bfu(v.z) * r2;
        float t3 = bfu(v.w) * r0;
        if (k == 0) { cf[0] = t0; cf[1] = t1; cf[2] = t2; cf[3] = t3; }
        a1[0] += t0; a1[1] += t1; a1[2] += t2; a1[3] += t3;
      }
      if (kend == 0) {                         // qm==0 or cnt==0: one row read
        const ushort4* rowv =
            reinterpret_cast<const ushort4*>(Fb + (size_t)sidx[g][0] * Ck) + j;
        ushort4 v = *rowv;
        cf[0] = bfu(v.x) * srel[g][0][a0];
        cf[1] = bfu(v.y) * srel[g][0][a1x];
        cf[2] = bfu(v.z) * srel[g][0][a2x];
        cf[3] = bfu(v.w) * srel[g][0][a0];
      }
      float pad = (float)(NSk - kend);
      float u[4];
      #pragma unroll
      for (int i2 = 0; i2 < 4; ++i2) {
        float a2v = a1[i2] + pad * cf[i2];
        u[i2] = (qmv > 0.f) ? a1[i2] * finv : cf[i2];
        accS2[i2] += a2v;
        accU[i2]  += u[i2];
        accU2[i2] += u[i2] * u[i2];
      }
      bf16 h0 = __float2bfloat16(u[0]);
      bf16 h1 = __float2bfloat16(u[1]);
      bf16 h2 = __float2bfloat16(u[2]);
      bf16 h3 = __float2bfloat16(u[3]);
      ushort4 uv = make_ushort4(*(unsigned short*)&h0, *(unsigned short*)&h1,
                                *(unsigned short*)&h2, *(unsigned short*)&h3);
      *(reinterpret_cast<ushort4*>(U + (size_t)q * Ck) + j) = uv;
    }
  }

  // cross-group LDS merge, then atomics from group 0
  __syncthreads();
  if (g == 1 && j < 72) {
    #pragma unroll
    for (int i2 = 0; i2 < 4; ++i2) {
      red[0][4 * j + i2] = accS2[i2];
      red[1][4 * j + i2] = accU[i2];
      red[2][4 * j + i2] = accU2[i2];
    }
  }
  __syncthreads();
  if (g == 0 && j < 72) {
    #pragma unroll
    for (int i2 = 0; i2 < 4; ++i2) {
      int c = 4 * j + i2;
      atomicAdd(&sums[b * Ck + c],               accS2[i2] + red[0][c]);
      atomicAdd(&sums[Bk * Ck + b * Ck + c],     accU[i2]  + red[1][c]);
      atomicAdd(&sums[2 * Bk * Ck + b * Ck + c], accU2[i2] + red[2][c]);
    }
  }

  // ---- tail: last block computes excite + LN fold ----
  __threadfence();
  __syncthreads();
  if (t == 0) {
    unsigned int old = atomicAdd(counter, 1u);
    isLast = (old == gridDim.x - 1) ? 1 : 0;
  }
  __syncthreads();
  if (!isLast) return;
  __threadfence();

  for (int i = t; i < Bk * Ck; i += 192)
    xgse[i] = atomicAdd(&sums[i], 0.f) * (1.f / 65536.f);
  __syncthreads();
  if (t < Bk * 18) {
    int bb = t / 18, h = t % 18;
    const float* w1r = w1 + h * Ck;
    float s = 0.f;
    for (int c = 0; c < Ck; ++c) s = fmaf(xgse[bb * Ck + c], w1r[c], s);
    xhid[t] = s > 0.f ? s : 0.f;
  }
  __syncthreads();
  for (int c = t; c < Ck; c += 192) {
    float m = 0.f, m2 = 0.f;
    float eb[Bk];
    #pragma unroll
    for (int bb = 0; bb < Bk; ++bb) {
      float s = 0.f;
      #pragma unroll
      for (int h = 0; h < 18; ++h) s += xhid[bb * 18 + h] * w2[c * 18 + h];
      float e = 1.f / (1.f + expf(-s));
      eb[bb] = e;
      m  += e * atomicAdd(&sums[Bk * Ck + bb * Ck + c], 0.f);
      m2 += e * e * atomicAdd(&sums[2 * Bk * Ck + bb * Ck + c], 0.f);
    }
    float mean = m * (1.f / 8192.f);
    float var  = m2 * (1.f / 8192.f) - mean * mean;
    float rsig = rsqrtf(var + 1e-5f);
    float gc = gamma[c];
    #pragma unroll
    for (int bb = 0; bb < Bk; ++bb) scaleA[bb * Ck + c] = gc * rsig * eb[bb];
    biasB[c] = beta[c] - gc * rsig * mean;
  }
}

// ---------------------------------------------------------------------------
// K2: finalize. Tiled transpose U [B,N1,C] bf16 -> out [B,C,N1] fp32 with
// out = relu(scaleA * u + biasB).
// ---------------------------------------------------------------------------
__global__ void k_finalize(const bf16* __restrict__ U, const float* __restrict__ scaleA,
                           const float* __restrict__ biasB, float* __restrict__ out) {
  __shared__ float tile[32][33];
  int b  = blockIdx.z;
  int cT = blockIdx.y * 32, nT = blockIdx.x * 32;
  int tx = threadIdx.x, ty = threadIdx.y;  // 32 x 8
  const bf16* Ub = U + (size_t)b * N1k * Ck;
  #pragma unroll
  for (int j = 0; j < 32; j += 8)
    tile[ty + j][tx] = __bfloat162float(Ub[(size_t)(nT + ty + j) * Ck + cT + tx]);
  __syncthreads();
  float* Ob = out + (size_t)b * Ck * N1k;
  #pragma unroll
  for (int j = 0; j < 32; j += 8) {
    int c = cT + ty + j;
    float v = scaleA[b * Ck + c] * tile[tx][ty + j] + biasB[c];
    Ob[(size_t)c * N1k + nT + tx] = v > 0.f ? v : 0.f;
  }
}

// ---------------------------------------------------------------------------
extern "C" void kernel_launch(void* const* d_in, const int* in_sizes, int n_in,
                              void* d_out, int out_size, void* d_ws, size_t ws_size,
                              hipStream_t stream) {
  const float* qxyz  = (const float*)d_in[0];
  const float* sxyz  = (const float*)d_in[1];
  const float* qm    = (const float*)d_in[2];
  const float* sm    = (const float*)d_in[3];
  const float* F     = (const float*)d_in[4];
  const float* w1    = (const float*)d_in[5];
  const float* w2    = (const float*)d_in[6];
  const float* gamma = (const float*)d_in[7];
  const float* beta  = (const float*)d_in[8];

  char* ws = (char*)d_ws;
  size_t off = 0;
  auto alloc = [&](size_t bytes) {
    off = (off + 255) & ~(size_t)255;
    void* p = ws + off;
    off += bytes;
    return p;
  };
  bf16*  Ftr    = (bf16*) alloc(sizeof(bf16)  * (size_t)Bk * N2k * Ck);
  bf16*  U      = (bf16*) alloc(sizeof(bf16)  * (size_t)Bk * N1k * Ck);
  int*   idxArr = (int*)  alloc(sizeof(int)   * (size_t)Bk * N1k * NSk);
  int*   cntArr = (int*)  alloc(sizeof(int)   * (size_t)Bk * N1k);
  float* sums   = (float*)alloc(sizeof(float) * 3 * Bk * Ck);
  float* scaleA = (float*)alloc(sizeof(float) * Bk * Ck);
  float* biasB  = (float*)alloc(sizeof(float) * Ck);
  unsigned int* counter = (unsigned int*)alloc(sizeof(unsigned int));

  k_pre<<<TRB + Bk * (N1k / 4), 256, 0, stream>>>(F, sxyz, sm, qxyz, qm, Ftr,
                                                  idxArr, cntArr, sums, counter);
  k_aggregate<<<Bk * (N1k / 4), 192, 0, stream>>>(Ftr, qxyz, sxyz, qm, idxArr, cntArr,
                                                  U, sums, w1, w2, gamma, beta,
                                                  scaleA, biasB, counter);
  k_finalize<<<dim3(N1k / 32, Ck / 32, Bk), dim3(32, 8), 0, stream>>>(U, scaleA, biasB,
                                                                      (float*)d_out);
}

// Round 9
// 112.112 us; speedup vs baseline: 1.8487x; 1.8487x over previous
//
#include <hip/hip_runtime.h>
#include <hip/hip_bf16.h>
#include <cstdint>
#include <cstddef>

static constexpr int Bk  = 4;
static constexpr int N1k = 2048;
static constexpr int N2k = 8192;
static constexpr int Ck  = 288;
static constexpr int NSk = 32;
static constexpr int TRB = (N2k / 32) * (Ck / 32) * Bk;   // 9216 transpose blocks

typedef __hip_bfloat16 bf16;

static __device__ __forceinline__ float bfu(unsigned short u) {
  return __uint_as_float((unsigned)u << 16);
}

// ---------------------------------------------------------------------------
// K0 (heterogeneous grid): blocks [0,TRB) transpose support_features
// [B,C,N2] fp32 -> Ftr [B,N2,C] bf16 (+ block 0 zeroes sums); blocks
// [TRB, TRB+2048) run the masked ball query (wave per query, 4 pts/lane/iter
// with scalar prefetch). BQ (latency-bound) overlaps the transpose stream.
// ---------------------------------------------------------------------------
__global__ __launch_bounds__(256) void k_pre(
    const float* __restrict__ F, const float* __restrict__ sxyz,
    const float* __restrict__ smask, const float* __restrict__ qxyz,
    const float* __restrict__ qmask, bf16* __restrict__ Ftr,
    int* __restrict__ idxArr, int* __restrict__ cntArr,
    float* __restrict__ sums) {
  __shared__ float tile[32][33];
  int t = threadIdx.x;

  if (blockIdx.x < TRB) {
    // ---- transpose part ----
    int i  = blockIdx.x;
    int sT = (i & 255) * 32;
    int yz = i >> 8;
    int cT = (yz % 9) * 32;
    int b  = yz / 9;
    int tx = t & 31, ty = t >> 5;      // 32 x 8
    const float* Fb = F + (size_t)b * Ck * N2k;
    #pragma unroll
    for (int j = 0; j < 32; j += 8)
      tile[ty + j][tx] = Fb[(size_t)(cT + ty + j) * N2k + sT + tx];
    if (i == 0) {
      for (int k = t; k < 3 * Bk * Ck; k += 256) sums[k] = 0.f;
    }
    __syncthreads();
    bf16* Ob = Ftr + (size_t)b * N2k * Ck;
    #pragma unroll
    for (int j = 0; j < 32; j += 8)
      Ob[(size_t)(sT + ty + j) * Ck + cT + tx] = __float2bfloat16(tile[tx][ty + j]);
    return;
  }

  // ---- ball query part ----
  int wave = (blockIdx.x - TRB) * 4 + (t >> 6);
  int lane = t & 63;
  int b = wave >> 11;                  // N1k = 2048
  int n = wave & (N1k - 1);
  int q = b * N1k + n;
  float qm = qmask[q];
  float qx = qxyz[q * 3 + 0];
  float qy = qxyz[q * 3 + 1];
  float qz = qxyz[q * 3 + 2];
  int cnt = 0, firstIdx = 0;
  int* myIdx = idxArr + (size_t)q * NSk;
  const float* Sx = sxyz + (size_t)b * N2k * 3;
  const float* Sm = smask + (size_t)b * N2k;
  if (qm > 0.f) {
    unsigned long long lmlt = (1ull << lane) - 1ull;
    float cx[4], cy[4], cz[4], cm[4];
    #pragma unroll
    for (int u = 0; u < 4; ++u) {
      int s = u * 64 + lane;
      cx[u] = Sx[3 * s]; cy[u] = Sx[3 * s + 1]; cz[u] = Sx[3 * s + 2];
      cm[u] = Sm[s];
    }
    for (int s0 = 0; s0 < N2k && cnt < NSk; s0 += 256) {
      float nx[4], ny[4], nz[4], nm[4];
      #pragma unroll
      for (int u = 0; u < 4; ++u) {
        int sp = s0 + 256 + u * 64 + lane;
        sp = (sp < N2k) ? sp : 0;      // clamped, unconditional prefetch
        nx[u] = Sx[3 * sp]; ny[u] = Sx[3 * sp + 1]; nz[u] = Sx[3 * sp + 2];
        nm[u] = Sm[sp];
      }
      #pragma unroll
      for (int u = 0; u < 4; ++u) {
        float dx = qx - cx[u], dy = qy - cy[u], dz = qz - cz[u];
        // match numpy association: (dx^2 + dy^2) + dz^2, no FMA contraction
        float d2 = __fadd_rn(__fadd_rn(__fmul_rn(dx, dx), __fmul_rn(dy, dy)),
                             __fmul_rn(dz, dz));
        bool valid = (d2 < 0.04f) && (cm[u] > 0.f);
        unsigned long long m = __ballot(valid);
        if (cnt == 0 && m != 0ull) firstIdx = s0 + u * 64 + (int)__builtin_ctzll(m);
        int p = cnt + (int)__popcll(m & lmlt);
        if (valid && p < NSk) myIdx[p] = s0 + u * 64 + lane;
        cnt += (int)__popcll(m);
      }
      #pragma unroll
      for (int u = 0; u < 4; ++u) {
        cx[u] = nx[u]; cy[u] = ny[u]; cz[u] = nz[u]; cm[u] = nm[u];
      }
    }
    if (cnt > NSk) cnt = NSk;
  }
  for (int p = cnt + lane; p < NSk; p += 64) myIdx[p] = firstIdx;
  if (lane == 0) cntArr[q] = cnt;
}

// ---------------------------------------------------------------------------
// K1: aggregation. Block = 192 = 2 groups x 96; group handles one query per
// "it" (2 its -> 4 queries/block -> 2048 blocks). b = blockIdx&3 pins XCDs
// to one batch's Ftr slice. Thread j<72 of a group owns channels [4j,4j+4)
// loaded as one ushort4 (8B). FIXED 32-iteration gather loop (compiler can
// pipeline loads); masked sum via uniform predicate k < m_end where
// m_end = qm>0 ? cnt : 32 (exactly the reference fm semantics, since pad
// slots repeat firstIdx and have fm=0 when qm>0, fm=1 when qm==0).
//  a2 = full 32-slot sum (unmasked, for gse); U = a1 / m_end.
// Per-(b,c) sums (S2, U, U^2) via cross-group LDS merge + atomics.
// ---------------------------------------------------------------------------
__global__ __launch_bounds__(192, 6) void k_aggregate(
    const bf16* __restrict__ Ftr, const float* __restrict__ qxyz,
    const float* __restrict__ sxyz, const float* __restrict__ qmask,
    const int* __restrict__ idxArr, const int* __restrict__ cntArr,
    bf16* __restrict__ U, float* __restrict__ sumS2,
    float* __restrict__ sumU, float* __restrict__ sumU2) {
  __shared__ int   sidx[2][NSk];
  __shared__ float srel[2][NSk][3];
  __shared__ int   scnt[2];
  __shared__ float sqm[2];
  __shared__ float red[3][Ck];

  int t = threadIdx.x;
  int b = blockIdx.x & 3;
  int nbase = (blockIdx.x >> 2) * 4;    // 512 blocks per batch, 4 queries each
  int g = t / 96;
  int j = t % 96;
  int a0 = j % 3, a1x = (a0 + 1) % 3, a2x = (a0 + 2) % 3;

  float accS2[4] = {0.f, 0.f, 0.f, 0.f};
  float accU[4]  = {0.f, 0.f, 0.f, 0.f};
  float accU2[4] = {0.f, 0.f, 0.f, 0.f};
  const bf16* Fb = Ftr + (size_t)b * N2k * Ck;

  for (int it = 0; it < 2; ++it) {
    int n = nbase + it * 2 + g;
    int q = b * N1k + n;
    __syncthreads();
    if (j < NSk) {
      int i = idxArr[(size_t)q * NSk + j];
      sidx[g][j] = i;
      float qx = qxyz[q * 3 + 0], qy = qxyz[q * 3 + 1], qz = qxyz[q * 3 + 2];
      srel[g][j][0] = (sxyz[(b * N2k + i) * 3 + 0] - qx) / 0.2f;
      srel[g][j][1] = (sxyz[(b * N2k + i) * 3 + 1] - qy) / 0.2f;
      srel[g][j][2] = (sxyz[(b * N2k + i) * 3 + 2] - qz) / 0.2f;
      if (j == 0) { scnt[g] = cntArr[q]; sqm[g] = qmask[q]; }
    }
    __syncthreads();

    int cnt   = scnt[g];
    float qmv = sqm[g];
    int m_end = (qmv > 0.f) ? cnt : NSk;      // fm_k = (k < m_end)
    float finv = (m_end > 0) ? (1.f / (float)m_end) : 0.f;

    if (j < 72) {
      float a1[4] = {0.f, 0.f, 0.f, 0.f};
      float a2[4] = {0.f, 0.f, 0.f, 0.f};
      #pragma unroll 8
      for (int k = 0; k < NSk; ++k) {
        const ushort4* rowv =
            reinterpret_cast<const ushort4*>(Fb + (size_t)sidx[g][k] * Ck) + j;
        ushort4 v = *rowv;
        float r0 = srel[g][k][a0];
        float r1 = srel[g][k][a1x];
        float r2 = srel[g][k][a2x];
        float t0 = bfu(v.x) * r0;
        float t1 = bfu(v.y) * r1;
        float t2 = bfu(v.z) * r2;
        float t3 = bfu(v.w) * r0;
        bool on = (k < m_end);
        a2[0] += t0; a2[1] += t1; a2[2] += t2; a2[3] += t3;
        a1[0] += on ? t0 : 0.f;
        a1[1] += on ? t1 : 0.f;
        a1[2] += on ? t2 : 0.f;
        a1[3] += on ? t3 : 0.f;
      }
      float u[4];
      #pragma unroll
      for (int i2 = 0; i2 < 4; ++i2) {
        u[i2] = a1[i2] * finv;
        accS2[i2] += a2[i2];
        accU[i2]  += u[i2];
        accU2[i2] += u[i2] * u[i2];
      }
      bf16 h0 = __float2bfloat16(u[0]);
      bf16 h1 = __float2bfloat16(u[1]);
      bf16 h2 = __float2bfloat16(u[2]);
      bf16 h3 = __float2bfloat16(u[3]);
      ushort4 uv = make_ushort4(*(unsigned short*)&h0, *(unsigned short*)&h1,
                                *(unsigned short*)&h2, *(unsigned short*)&h3);
      *(reinterpret_cast<ushort4*>(U + (size_t)q * Ck) + j) = uv;
    }
  }

  // cross-group LDS merge, then atomics from group 0
  __syncthreads();
  if (g == 1 && j < 72) {
    #pragma unroll
    for (int i2 = 0; i2 < 4; ++i2) {
      red[0][4 * j + i2] = accS2[i2];
      red[1][4 * j + i2] = accU[i2];
      red[2][4 * j + i2] = accU2[i2];
    }
  }
  __syncthreads();
  if (g == 0 && j < 72) {
    #pragma unroll
    for (int i2 = 0; i2 < 4; ++i2) {
      int c = 4 * j + i2;
      atomicAdd(&sumS2[b * Ck + c], accS2[i2] + red[0][c]);
      atomicAdd(&sumU[b * Ck + c],  accU[i2]  + red[1][c]);
      atomicAdd(&sumU2[b * Ck + c], accU2[i2] + red[2][c]);
    }
  }
}

// ---------------------------------------------------------------------------
// K2: gse -> MLP -> sigmoid excite, ONCE in a single block; fold excite + LN
// stats into per-(b,c) scaleA and per-c biasB.
// ---------------------------------------------------------------------------
__global__ __launch_bounds__(288) void k_excite(
    const float* __restrict__ sumS2, const float* __restrict__ sumU,
    const float* __restrict__ sumU2, const float* __restrict__ w1,
    const float* __restrict__ w2, const float* __restrict__ gamma,
    const float* __restrict__ beta, float* __restrict__ scaleA,
    float* __restrict__ biasB) {
  __shared__ float gse[Bk * Ck];
  __shared__ float hid[Bk * 18];
  int t = threadIdx.x;
  for (int i = t; i < Bk * Ck; i += 288) gse[i] = sumS2[i] * (1.f / 65536.f);
  __syncthreads();
  if (t < Bk * 18) {
    int b = t / 18, h = t % 18;
    float s = 0.f;
    for (int c = 0; c < Ck; ++c) s += gse[b * Ck + c] * w1[h * Ck + c];
    hid[t] = s > 0.f ? s : 0.f;
  }
  __syncthreads();
  if (t < Ck) {
    int c = t;
    float m = 0.f, m2 = 0.f;
    float eb[Bk];
    #pragma unroll
    for (int b = 0; b < Bk; ++b) {
      float s = 0.f;
      #pragma unroll
      for (int h = 0; h < 18; ++h) s += hid[b * 18 + h] * w2[c * 18 + h];
      float e = 1.f / (1.f + expf(-s));
      eb[b] = e;
      m  += e * sumU[b * Ck + c];
      m2 += e * e * sumU2[b * Ck + c];
    }
    float mean = m * (1.f / 8192.f);
    float ex2  = m2 * (1.f / 8192.f);
    float var  = ex2 - mean * mean;
    float rsig = rsqrtf(var + 1e-5f);
    float gc = gamma[c];
    #pragma unroll
    for (int b = 0; b < Bk; ++b) scaleA[b * Ck + c] = gc * rsig * eb[b];
    biasB[c] = beta[c] - gc * rsig * mean;
  }
}

// ---------------------------------------------------------------------------
// K3: finalize. Tiled transpose U [B,N1,C] bf16 -> out [B,C,N1] fp32 with
// out = relu(scaleA * u + biasB).
// ---------------------------------------------------------------------------
__global__ void k_finalize(const bf16* __restrict__ U, const float* __restrict__ scaleA,
                           const float* __restrict__ biasB, float* __restrict__ out) {
  __shared__ float tile[32][33];
  int b  = blockIdx.z;
  int cT = blockIdx.y * 32, nT = blockIdx.x * 32;
  int tx = threadIdx.x, ty = threadIdx.y;  // 32 x 8
  const bf16* Ub = U + (size_t)b * N1k * Ck;
  #pragma unroll
  for (int j = 0; j < 32; j += 8)
    tile[ty + j][tx] = __bfloat162float(Ub[(size_t)(nT + ty + j) * Ck + cT + tx]);
  __syncthreads();
  float* Ob = out + (size_t)b * Ck * N1k;
  #pragma unroll
  for (int j = 0; j < 32; j += 8) {
    int c = cT + ty + j;
    float v = scaleA[b * Ck + c] * tile[tx][ty + j] + biasB[c];
    Ob[(size_t)c * N1k + nT + tx] = v > 0.f ? v : 0.f;
  }
}

// ---------------------------------------------------------------------------
extern "C" void kernel_launch(void* const* d_in, const int* in_sizes, int n_in,
                              void* d_out, int out_size, void* d_ws, size_t ws_size,
                              hipStream_t stream) {
  const float* qxyz  = (const float*)d_in[0];
  const float* sxyz  = (const float*)d_in[1];
  const float* qm    = (const float*)d_in[2];
  const float* sm    = (const float*)d_in[3];
  const float* F     = (const float*)d_in[4];
  const float* w1    = (const float*)d_in[5];
  const float* w2    = (const float*)d_in[6];
  const float* gamma = (const float*)d_in[7];
  const float* beta  = (const float*)d_in[8];

  char* ws = (char*)d_ws;
  size_t off = 0;
  auto alloc = [&](size_t bytes) {
    off = (off + 255) & ~(size_t)255;
    void* p = ws + off;
    off += bytes;
    return p;
  };
  bf16*  Ftr    = (bf16*) alloc(sizeof(bf16)  * (size_t)Bk * N2k * Ck);
  bf16*  U      = (bf16*) alloc(sizeof(bf16)  * (size_t)Bk * N1k * Ck);
  int*   idxArr = (int*)  alloc(sizeof(int)   * (size_t)Bk * N1k * NSk);
  int*   cntArr = (int*)  alloc(sizeof(int)   * (size_t)Bk * N1k);
  float* sums   = (float*)alloc(sizeof(float) * 3 * Bk * Ck);
  float* sumS2 = sums;
  float* sumU  = sums + Bk * Ck;
  float* sumU2 = sums + 2 * Bk * Ck;
  float* scaleA = (float*)alloc(sizeof(float) * Bk * Ck);
  float* biasB  = (float*)alloc(sizeof(float) * Ck);

  k_pre<<<TRB + Bk * (N1k / 4), 256, 0, stream>>>(F, sxyz, sm, qxyz, qm, Ftr,
                                                  idxArr, cntArr, sums);
  k_aggregate<<<Bk * (N1k / 4), 192, 0, stream>>>(Ftr, qxyz, sxyz, qm, idxArr, cntArr,
                                                  U, sumS2, sumU, sumU2);
  k_excite<<<1, 288, 0, stream>>>(sumS2, sumU, sumU2, w1, w2, gamma, beta, scaleA, biasB);
  k_finalize<<<dim3(N1k / 32, Ck / 32, Bk), dim3(32, 8), 0, stream>>>(U, scaleA, biasB,
                                                                      (float*)d_out);
}

// Round 10
// 79.586 us; speedup vs baseline: 2.6043x; 1.4087x over previous
//
#include <hip/hip_runtime.h>
#include <hip/hip_bf16.h>
#include <cstdint>
#include <cstddef>

static constexpr int Bk  = 4;
static constexpr int N1k = 2048;
static constexpr int N2k = 8192;
static constexpr int Ck  = 288;
static constexpr int NSk = 32;
static constexpr int BQB = Bk * (N1k / 4);                // 2048 ball-query blocks
static constexpr int TRB = (N2k / 32) * (Ck / 32) * Bk;   // 9216 transpose blocks

typedef __hip_bfloat16 bf16;

// ---------------------------------------------------------------------------
// K0 (heterogeneous grid): blocks [0,BQB) run the masked ball query (wave per
// query, 4 pts/lane/iter with scalar prefetch) — FIRST, so their long-tail
// waves overlap the transpose stream. Blocks [BQB, BQB+TRB) transpose
// support_features [B,C,N2] fp32 -> Ftr [B,N2,C] bf16 (+ first transpose
// block zeroes sums).
// ---------------------------------------------------------------------------
__global__ __launch_bounds__(256) void k_pre(
    const float* __restrict__ F, const float* __restrict__ sxyz,
    const float* __restrict__ smask, const float* __restrict__ qxyz,
    const float* __restrict__ qmask, bf16* __restrict__ Ftr,
    int* __restrict__ idxArr, int* __restrict__ cntArr,
    float* __restrict__ sums) {
  __shared__ float tile[32][33];
  int t = threadIdx.x;

  if (blockIdx.x >= BQB) {
    // ---- transpose part ----
    int i  = blockIdx.x - BQB;
    int sT = (i & 255) * 32;
    int yz = i >> 8;
    int cT = (yz % 9) * 32;
    int b  = yz / 9;
    int tx = t & 31, ty = t >> 5;      // 32 x 8
    const float* Fb = F + (size_t)b * Ck * N2k;
    #pragma unroll
    for (int j = 0; j < 32; j += 8)
      tile[ty + j][tx] = Fb[(size_t)(cT + ty + j) * N2k + sT + tx];
    if (i == 0) {
      for (int k = t; k < 3 * Bk * Ck; k += 256) sums[k] = 0.f;
    }
    __syncthreads();
    bf16* Ob = Ftr + (size_t)b * N2k * Ck;
    #pragma unroll
    for (int j = 0; j < 32; j += 8)
      Ob[(size_t)(sT + ty + j) * Ck + cT + tx] = __float2bfloat16(tile[tx][ty + j]);
    return;
  }

  // ---- ball query part ----
  int wave = blockIdx.x * 4 + (t >> 6);
  int lane = t & 63;
  int b = wave >> 11;                  // N1k = 2048
  int n = wave & (N1k - 1);
  int q = b * N1k + n;
  float qm = qmask[q];
  float qx = qxyz[q * 3 + 0];
  float qy = qxyz[q * 3 + 1];
  float qz = qxyz[q * 3 + 2];
  int cnt = 0, firstIdx = 0;
  int* myIdx = idxArr + (size_t)q * NSk;
  const float* Sx = sxyz + (size_t)b * N2k * 3;
  const float* Sm = smask + (size_t)b * N2k;
  if (qm > 0.f) {
    unsigned long long lmlt = (1ull << lane) - 1ull;
    float cx[4], cy[4], cz[4], cm[4];
    #pragma unroll
    for (int u = 0; u < 4; ++u) {
      int s = u * 64 + lane;
      cx[u] = Sx[3 * s]; cy[u] = Sx[3 * s + 1]; cz[u] = Sx[3 * s + 2];
      cm[u] = Sm[s];
    }
    for (int s0 = 0; s0 < N2k && cnt < NSk; s0 += 256) {
      float nx[4], ny[4], nz[4], nm[4];
      #pragma unroll
      for (int u = 0; u < 4; ++u) {
        int sp = s0 + 256 + u * 64 + lane;
        sp = (sp < N2k) ? sp : 0;      // clamped, unconditional prefetch
        nx[u] = Sx[3 * sp]; ny[u] = Sx[3 * sp + 1]; nz[u] = Sx[3 * sp + 2];
        nm[u] = Sm[sp];
      }
      #pragma unroll
      for (int u = 0; u < 4; ++u) {
        float dx = qx - cx[u], dy = qy - cy[u], dz = qz - cz[u];
        // match numpy association: (dx^2 + dy^2) + dz^2, no FMA contraction
        float d2 = __fadd_rn(__fadd_rn(__fmul_rn(dx, dx), __fmul_rn(dy, dy)),
                             __fmul_rn(dz, dz));
        bool valid = (d2 < 0.04f) && (cm[u] > 0.f);
        unsigned long long m = __ballot(valid);
        if (cnt == 0 && m != 0ull) firstIdx = s0 + u * 64 + (int)__builtin_ctzll(m);
        int p = cnt + (int)__popcll(m & lmlt);
        if (valid && p < NSk) myIdx[p] = s0 + u * 64 + lane;
        cnt += (int)__popcll(m);
      }
      #pragma unroll
      for (int u = 0; u < 4; ++u) {
        cx[u] = nx[u]; cy[u] = ny[u]; cz[u] = nz[u]; cm[u] = nm[u];
      }
    }
    if (cnt > NSk) cnt = NSk;
  }
  for (int p = cnt + lane; p < NSk; p += 64) myIdx[p] = firstIdx;
  if (lane == 0) cntArr[q] = cnt;
}

// ---------------------------------------------------------------------------
// K1: main aggregation (R4-proven structure; unroll 16 for deeper load
// pipeline). Block = 192 threads = 2 groups x 96; each group handles one
// query per "it"; 2 its -> 4 queries/block -> 2048 blocks. b = blockIdx&3
// pins XCDs (round-robin dispatch) to one batch's Ftr slice.
// Thread j of a group owns channels {j, j+96, j+192} (all share rel axis j%3).
//  a2[c] = sum_k F[idx_k][c] * rel[k][c%3]                (unmasked, for gse)
//  a1[c] = sum_k F[idx_k][c] * rel[k][c%3] * fm[k]        (masked)
//  U[b,n,c] = a1 / sum_k fm[k]   (stored bf16)
// Per-(b,c) sums (gse, sumU, sumU2) via cross-group LDS merge + atomics.
// ---------------------------------------------------------------------------
__global__ __launch_bounds__(192, 6) void k_aggregate(
    const bf16* __restrict__ Ftr, const float* __restrict__ qxyz,
    const float* __restrict__ sxyz, const float* __restrict__ qmask,
    const int* __restrict__ idxArr, const int* __restrict__ cntArr,
    bf16* __restrict__ U, float* __restrict__ sumS2,
    float* __restrict__ sumU, float* __restrict__ sumU2) {
  __shared__ int   sidx[2][NSk];
  __shared__ float srel[2][NSk][3];
  __shared__ float srelm[2][NSk][3];
  __shared__ float sfinv[2];
  __shared__ float red[9][96];

  int b     = blockIdx.x & 3;
  int nbase = (blockIdx.x >> 2) * 4;    // 512 blocks per batch, 4 queries each
  int g = threadIdx.x / 96;
  int j = threadIdx.x % 96;
  int a = j % 3;

  float sS2[3]  = {0.f, 0.f, 0.f};
  float sUa[3]  = {0.f, 0.f, 0.f};
  float sU2a[3] = {0.f, 0.f, 0.f};

  const bf16* Fb = Ftr + (size_t)b * N2k * Ck;

  for (int it = 0; it < 2; ++it) {
    int n = nbase + it * 2 + g;
    int q = b * N1k + n;
    __syncthreads();
    if (j < NSk) {
      int k = j;
      int i = idxArr[(size_t)q * NSk + k];
      sidx[g][k] = i;
      float qx = qxyz[q * 3 + 0], qy = qxyz[q * 3 + 1], qz = qxyz[q * 3 + 2];
      float sx = sxyz[(b * N2k + i) * 3 + 0];
      float sy = sxyz[(b * N2k + i) * 3 + 1];
      float sz = sxyz[(b * N2k + i) * 3 + 2];
      float rx = (sx - qx) / 0.2f;
      float ry = (sy - qy) / 0.2f;
      float rz = (sz - qz) / 0.2f;
      float qmv = qmask[q];
      int fnd = cntArr[q];
      float fmk = (qmv > 0.f) ? ((k < fnd) ? 1.f : 0.f) : 1.f;
      srel[g][k][0] = rx; srel[g][k][1] = ry; srel[g][k][2] = rz;
      srelm[g][k][0] = rx * fmk; srelm[g][k][1] = ry * fmk; srelm[g][k][2] = rz * fmk;
      if (k == 0) {
        float fmsum = (qmv > 0.f) ? (float)fnd : (float)NSk;
        sfinv[g] = (fmsum > 0.f) ? (1.f / fmsum) : 0.f;
      }
    }
    __syncthreads();

    float a1[3] = {0.f, 0.f, 0.f};
    float a2[3] = {0.f, 0.f, 0.f};
    #pragma unroll 16
    for (int k = 0; k < NSk; ++k) {
      const bf16* row = Fb + (size_t)sidx[g][k] * Ck;
      float f0 = __bfloat162float(row[j]);
      float f1 = __bfloat162float(row[j + 96]);
      float f2 = __bfloat162float(row[j + 192]);
      float r  = srel[g][k][a];
      float rm = srelm[g][k][a];
      a2[0] = fmaf(f0, r, a2[0]);
      a2[1] = fmaf(f1, r, a2[1]);
      a2[2] = fmaf(f2, r, a2[2]);
      a1[0] = fmaf(f0, rm, a1[0]);
      a1[1] = fmaf(f1, rm, a1[1]);
      a1[2] = fmaf(f2, rm, a1[2]);
    }
    float finv = sfinv[g];
    float u0 = a1[0] * finv, u1 = a1[1] * finv, u2 = a1[2] * finv;
    bf16* Urow = U + (size_t)q * Ck;
    Urow[j]       = __float2bfloat16(u0);
    Urow[j + 96]  = __float2bfloat16(u1);
    Urow[j + 192] = __float2bfloat16(u2);
    sS2[0] += a2[0]; sS2[1] += a2[1]; sS2[2] += a2[2];
    sUa[0] += u0;    sUa[1] += u1;    sUa[2] += u2;
    sU2a[0] += u0 * u0; sU2a[1] += u1 * u1; sU2a[2] += u2 * u2;
  }

  // cross-group merge in LDS, then one set of atomics from group 0
  __syncthreads();
  if (g == 1) {
    red[0][j] = sS2[0];  red[1][j] = sS2[1];  red[2][j] = sS2[2];
    red[3][j] = sUa[0];  red[4][j] = sUa[1];  red[5][j] = sUa[2];
    red[6][j] = sU2a[0]; red[7][j] = sU2a[1]; red[8][j] = sU2a[2];
  }
  __syncthreads();
  if (g == 0) {
    float* pS2 = sumS2 + b * Ck;
    float* pU  = sumU  + b * Ck;
    float* pU2 = sumU2 + b * Ck;
    atomicAdd(&pS2[j],       sS2[0]  + red[0][j]);
    atomicAdd(&pS2[j + 96],  sS2[1]  + red[1][j]);
    atomicAdd(&pS2[j + 192], sS2[2]  + red[2][j]);
    atomicAdd(&pU[j],        sUa[0]  + red[3][j]);
    atomicAdd(&pU[j + 96],   sUa[1]  + red[4][j]);
    atomicAdd(&pU[j + 192],  sUa[2]  + red[5][j]);
    atomicAdd(&pU2[j],       sU2a[0] + red[6][j]);
    atomicAdd(&pU2[j + 96],  sU2a[1] + red[7][j]);
    atomicAdd(&pU2[j + 192], sU2a[2] + red[8][j]);
  }
}

// ---------------------------------------------------------------------------
// K2: gse -> MLP -> sigmoid excite, ONCE in a single block; fold excite + LN
// stats into per-(b,c) scaleA and per-c biasB.
// ---------------------------------------------------------------------------
__global__ __launch_bounds__(288) void k_excite(
    const float* __restrict__ sumS2, const float* __restrict__ sumU,
    const float* __restrict__ sumU2, const float* __restrict__ w1,
    const float* __restrict__ w2, const float* __restrict__ gamma,
    const float* __restrict__ beta, float* __restrict__ scaleA,
    float* __restrict__ biasB) {
  __shared__ float gse[Bk * Ck];
  __shared__ float hid[Bk * 18];
  int t = threadIdx.x;
  for (int i = t; i < Bk * Ck; i += 288) gse[i] = sumS2[i] * (1.f / 65536.f);
  __syncthreads();
  if (t < Bk * 18) {
    int b = t / 18, h = t % 18;
    float s = 0.f;
    for (int c = 0; c < Ck; ++c) s += gse[b * Ck + c] * w1[h * Ck + c];
    hid[t] = s > 0.f ? s : 0.f;
  }
  __syncthreads();
  if (t < Ck) {
    int c = t;
    float m = 0.f, m2 = 0.f;
    float eb[Bk];
    #pragma unroll
    for (int b = 0; b < Bk; ++b) {
      float s = 0.f;
      #pragma unroll
      for (int h = 0; h < 18; ++h) s += hid[b * 18 + h] * w2[c * 18 + h];
      float e = 1.f / (1.f + expf(-s));
      eb[b] = e;
      m  += e * sumU[b * Ck + c];
      m2 += e * e * sumU2[b * Ck + c];
    }
    float mean = m * (1.f / 8192.f);
    float ex2  = m2 * (1.f / 8192.f);
    float var  = ex2 - mean * mean;
    float rsig = rsqrtf(var + 1e-5f);
    float gc = gamma[c];
    #pragma unroll
    for (int b = 0; b < Bk; ++b) scaleA[b * Ck + c] = gc * rsig * eb[b];
    biasB[c] = beta[c] - gc * rsig * mean;
  }
}

// ---------------------------------------------------------------------------
// K3: finalize. Tiled transpose U [B,N1,C] bf16 -> out [B,C,N1] fp32 with
// out = relu(scaleA * u + biasB).
// ---------------------------------------------------------------------------
__global__ void k_finalize(const bf16* __restrict__ U, const float* __restrict__ scaleA,
                           const float* __restrict__ biasB, float* __restrict__ out) {
  __shared__ float tile[32][33];
  int b  = blockIdx.z;
  int cT = blockIdx.y * 32, nT = blockIdx.x * 32;
  int tx = threadIdx.x, ty = threadIdx.y;  // 32 x 8
  const bf16* Ub = U + (size_t)b * N1k * Ck;
  #pragma unroll
  for (int j = 0; j < 32; j += 8)
    tile[ty + j][tx] = __bfloat162float(Ub[(size_t)(nT + ty + j) * Ck + cT + tx]);
  __syncthreads();
  float* Ob = out + (size_t)b * Ck * N1k;
  #pragma unroll
  for (int j = 0; j < 32; j += 8) {
    int c = cT + ty + j;
    float v = scaleA[b * Ck + c] * tile[tx][ty + j] + biasB[c];
    Ob[(size_t)c * N1k + nT + tx] = v > 0.f ? v : 0.f;
  }
}

// ---------------------------------------------------------------------------
extern "C" void kernel_launch(void* const* d_in, const int* in_sizes, int n_in,
                              void* d_out, int out_size, void* d_ws, size_t ws_size,
                              hipStream_t stream) {
  const float* qxyz  = (const float*)d_in[0];
  const float* sxyz  = (const float*)d_in[1];
  const float* qm    = (const float*)d_in[2];
  const float* sm    = (const float*)d_in[3];
  const float* F     = (const float*)d_in[4];
  const float* w1    = (const float*)d_in[5];
  const float* w2    = (const float*)d_in[6];
  const float* gamma = (const float*)d_in[7];
  const float* beta  = (const float*)d_in[8];

  char* ws = (char*)d_ws;
  size_t off = 0;
  auto alloc = [&](size_t bytes) {
    off = (off + 255) & ~(size_t)255;
    void* p = ws + off;
    off += bytes;
    return p;
  };
  bf16*  Ftr    = (bf16*) alloc(sizeof(bf16)  * (size_t)Bk * N2k * Ck);
  bf16*  U      = (bf16*) alloc(sizeof(bf16)  * (size_t)Bk * N1k * Ck);
  int*   idxArr = (int*)  alloc(sizeof(int)   * (size_t)Bk * N1k * NSk);
  int*   cntArr = (int*)  alloc(sizeof(int)   * (size_t)Bk * N1k);
  float* sums   = (float*)alloc(sizeof(float) * 3 * Bk * Ck);
  float* sumS2 = sums;
  float* sumU  = sums + Bk * Ck;
  float* sumU2 = sums + 2 * Bk * Ck;
  float* scaleA = (float*)alloc(sizeof(float) * Bk * Ck);
  float* biasB  = (float*)alloc(sizeof(float) * Ck);

  k_pre<<<BQB + TRB, 256, 0, stream>>>(F, sxyz, sm, qxyz, qm, Ftr,
                                       idxArr, cntArr, sums);
  k_aggregate<<<Bk * (N1k / 4), 192, 0, stream>>>(Ftr, qxyz, sxyz, qm, idxArr, cntArr,
                                                  U, sumS2, sumU, sumU2);
  k_excite<<<1, 288, 0, stream>>>(sumS2, sumU, sumU2, w1, w2, gamma, beta, scaleA, biasB);
  k_finalize<<<dim3(N1k / 32, Ck / 32, Bk), dim3(32, 8), 0, stream>>>(U, scaleA, biasB,
                                                                      (float*)d_out);
}

// Round 11
// 78.056 us; speedup vs baseline: 2.6553x; 1.0196x over previous
//
#include <hip/hip_runtime.h>
#include <hip/hip_bf16.h>
#include <cstdint>
#include <cstddef>

static constexpr int Bk  = 4;
static constexpr int N1k = 2048;
static constexpr int N2k = 8192;
static constexpr int Ck  = 288;
static constexpr int NSk = 32;
static constexpr int TRB = (N2k / 32) * (Ck / 32) * Bk;   // 9216 transpose blocks

typedef __hip_bfloat16 bf16;

// ---------------------------------------------------------------------------
// K0 (heterogeneous grid): blocks [0,TRB) transpose support_features
// [B,C,N2] fp32 -> Ftr [B,N2,C] bf16 (+ block 0 zeroes sums); blocks
// [TRB, TRB+2048) run the masked ball query (wave per query, 4 pts/lane/iter
// with scalar prefetch). Transpose FIRST (the HBM stream k_aggregate waits
// on); BQ tail waves overlap the stream's tail.
// ---------------------------------------------------------------------------
__global__ __launch_bounds__(256) void k_pre(
    const float* __restrict__ F, const float* __restrict__ sxyz,
    const float* __restrict__ smask, const float* __restrict__ qxyz,
    const float* __restrict__ qmask, bf16* __restrict__ Ftr,
    int* __restrict__ idxArr, int* __restrict__ cntArr,
    float* __restrict__ sums) {
  __shared__ float tile[32][33];
  int t = threadIdx.x;

  if (blockIdx.x < TRB) {
    // ---- transpose part ----
    int i  = blockIdx.x;
    int sT = (i & 255) * 32;
    int yz = i >> 8;
    int cT = (yz % 9) * 32;
    int b  = yz / 9;
    int tx = t & 31, ty = t >> 5;      // 32 x 8
    const float* Fb = F + (size_t)b * Ck * N2k;
    #pragma unroll
    for (int j = 0; j < 32; j += 8)
      tile[ty + j][tx] = Fb[(size_t)(cT + ty + j) * N2k + sT + tx];
    if (i == 0) {
      for (int k = t; k < 3 * Bk * Ck; k += 256) sums[k] = 0.f;
    }
    __syncthreads();
    bf16* Ob = Ftr + (size_t)b * N2k * Ck;
    #pragma unroll
    for (int j = 0; j < 32; j += 8)
      Ob[(size_t)(sT + ty + j) * Ck + cT + tx] = __float2bfloat16(tile[tx][ty + j]);
    return;
  }

  // ---- ball query part ----
  int wave = (blockIdx.x - TRB) * 4 + (t >> 6);
  int lane = t & 63;
  int b = wave >> 11;                  // N1k = 2048
  int n = wave & (N1k - 1);
  int q = b * N1k + n;
  float qm = qmask[q];
  float qx = qxyz[q * 3 + 0];
  float qy = qxyz[q * 3 + 1];
  float qz = qxyz[q * 3 + 2];
  int cnt = 0, firstIdx = 0;
  int* myIdx = idxArr + (size_t)q * NSk;
  const float* Sx = sxyz + (size_t)b * N2k * 3;
  const float* Sm = smask + (size_t)b * N2k;
  if (qm > 0.f) {
    unsigned long long lmlt = (1ull << lane) - 1ull;
    float cx[4], cy[4], cz[4], cm[4];
    #pragma unroll
    for (int u = 0; u < 4; ++u) {
      int s = u * 64 + lane;
      cx[u] = Sx[3 * s]; cy[u] = Sx[3 * s + 1]; cz[u] = Sx[3 * s + 2];
      cm[u] = Sm[s];
    }
    for (int s0 = 0; s0 < N2k && cnt < NSk; s0 += 256) {
      float nx[4], ny[4], nz[4], nm[4];
      #pragma unroll
      for (int u = 0; u < 4; ++u) {
        int sp = s0 + 256 + u * 64 + lane;
        sp = (sp < N2k) ? sp : 0;      // clamped, unconditional prefetch
        nx[u] = Sx[3 * sp]; ny[u] = Sx[3 * sp + 1]; nz[u] = Sx[3 * sp + 2];
        nm[u] = Sm[sp];
      }
      #pragma unroll
      for (int u = 0; u < 4; ++u) {
        float dx = qx - cx[u], dy = qy - cy[u], dz = qz - cz[u];
        // match numpy association: (dx^2 + dy^2) + dz^2, no FMA contraction
        float d2 = __fadd_rn(__fadd_rn(__fmul_rn(dx, dx), __fmul_rn(dy, dy)),
                             __fmul_rn(dz, dz));
        bool valid = (d2 < 0.04f) && (cm[u] > 0.f);
        unsigned long long m = __ballot(valid);
        if (cnt == 0 && m != 0ull) firstIdx = s0 + u * 64 + (int)__builtin_ctzll(m);
        int p = cnt + (int)__popcll(m & lmlt);
        if (valid && p < NSk) myIdx[p] = s0 + u * 64 + lane;
        cnt += (int)__popcll(m);
      }
      #pragma unroll
      for (int u = 0; u < 4; ++u) {
        cx[u] = nx[u]; cy[u] = ny[u]; cz[u] = nz[u]; cm[u] = nm[u];
      }
    }
    if (cnt > NSk) cnt = NSk;
  }
  for (int p = cnt + lane; p < NSk; p += 64) myIdx[p] = firstIdx;
  if (lane == 0) cntArr[q] = cnt;
}

// ---------------------------------------------------------------------------
// K1: main aggregation (R7 body; 2 queries/block x 4096 blocks for backfill
// occupancy). Block = 192 threads = 2 groups x 96; each group handles one
// query. b = blockIdx&3 pins XCDs (round-robin dispatch) to one batch's Ftr
// slice. Thread j of a group owns channels {j, j+96, j+192} (rel axis j%3).
//  a2[c] = sum_k F[idx_k][c] * rel[k][c%3]                (unmasked, for gse)
//  a1[c] = sum_k F[idx_k][c] * rel[k][c%3] * fm[k]        (masked)
//  U[b,n,c] = a1 / sum_k fm[k]   (stored bf16)
// Per-(b,c) sums (gse, sumU, sumU2) via cross-group LDS merge + atomics.
// ---------------------------------------------------------------------------
__global__ __launch_bounds__(192, 6) void k_aggregate(
    const bf16* __restrict__ Ftr, const float* __restrict__ qxyz,
    const float* __restrict__ sxyz, const float* __restrict__ qmask,
    const int* __restrict__ idxArr, const int* __restrict__ cntArr,
    bf16* __restrict__ U, float* __restrict__ sumS2,
    float* __restrict__ sumU, float* __restrict__ sumU2) {
  __shared__ int   sidx[2][NSk];
  __shared__ float srel[2][NSk][3];
  __shared__ float srelm[2][NSk][3];
  __shared__ float sfinv[2];
  __shared__ float red[9][96];

  int b     = blockIdx.x & 3;
  int nbase = (blockIdx.x >> 2) * 2;    // 1024 blocks per batch, 2 queries each
  int g = threadIdx.x / 96;
  int j = threadIdx.x % 96;
  int a = j % 3;

  const bf16* Fb = Ftr + (size_t)b * N2k * Ck;

  int n = nbase + g;
  int q = b * N1k + n;
  if (j < NSk) {
    int k = j;
    int i = idxArr[(size_t)q * NSk + k];
    sidx[g][k] = i;
    float qx = qxyz[q * 3 + 0], qy = qxyz[q * 3 + 1], qz = qxyz[q * 3 + 2];
    float sx = sxyz[(b * N2k + i) * 3 + 0];
    float sy = sxyz[(b * N2k + i) * 3 + 1];
    float sz = sxyz[(b * N2k + i) * 3 + 2];
    float rx = (sx - qx) / 0.2f;
    float ry = (sy - qy) / 0.2f;
    float rz = (sz - qz) / 0.2f;
    float qmv = qmask[q];
    int fnd = cntArr[q];
    float fmk = (qmv > 0.f) ? ((k < fnd) ? 1.f : 0.f) : 1.f;
    srel[g][k][0] = rx; srel[g][k][1] = ry; srel[g][k][2] = rz;
    srelm[g][k][0] = rx * fmk; srelm[g][k][1] = ry * fmk; srelm[g][k][2] = rz * fmk;
    if (k == 0) {
      float fmsum = (qmv > 0.f) ? (float)fnd : (float)NSk;
      sfinv[g] = (fmsum > 0.f) ? (1.f / fmsum) : 0.f;
    }
  }
  __syncthreads();

  float a1[3] = {0.f, 0.f, 0.f};
  float a2[3] = {0.f, 0.f, 0.f};
  #pragma unroll 8
  for (int k = 0; k < NSk; ++k) {
    const bf16* row = Fb + (size_t)sidx[g][k] * Ck;
    float f0 = __bfloat162float(row[j]);
    float f1 = __bfloat162float(row[j + 96]);
    float f2 = __bfloat162float(row[j + 192]);
    float r  = srel[g][k][a];
    float rm = srelm[g][k][a];
    a2[0] = fmaf(f0, r, a2[0]);
    a2[1] = fmaf(f1, r, a2[1]);
    a2[2] = fmaf(f2, r, a2[2]);
    a1[0] = fmaf(f0, rm, a1[0]);
    a1[1] = fmaf(f1, rm, a1[1]);
    a1[2] = fmaf(f2, rm, a1[2]);
  }
  float finv = sfinv[g];
  float u0 = a1[0] * finv, u1 = a1[1] * finv, u2 = a1[2] * finv;
  bf16* Urow = U + (size_t)q * Ck;
  Urow[j]       = __float2bfloat16(u0);
  Urow[j + 96]  = __float2bfloat16(u1);
  Urow[j + 192] = __float2bfloat16(u2);

  // cross-group merge in LDS, then one set of atomics from group 0
  __syncthreads();
  if (g == 1) {
    red[0][j] = a2[0];      red[1][j] = a2[1];      red[2][j] = a2[2];
    red[3][j] = u0;         red[4][j] = u1;         red[5][j] = u2;
    red[6][j] = u0 * u0;    red[7][j] = u1 * u1;    red[8][j] = u2 * u2;
  }
  __syncthreads();
  if (g == 0) {
    float* pS2 = sumS2 + b * Ck;
    float* pU  = sumU  + b * Ck;
    float* pU2 = sumU2 + b * Ck;
    atomicAdd(&pS2[j],       a2[0]   + red[0][j]);
    atomicAdd(&pS2[j + 96],  a2[1]   + red[1][j]);
    atomicAdd(&pS2[j + 192], a2[2]   + red[2][j]);
    atomicAdd(&pU[j],        u0      + red[3][j]);
    atomicAdd(&pU[j + 96],   u1      + red[4][j]);
    atomicAdd(&pU[j + 192],  u2      + red[5][j]);
    atomicAdd(&pU2[j],       u0 * u0 + red[6][j]);
    atomicAdd(&pU2[j + 96],  u1 * u1 + red[7][j]);
    atomicAdd(&pU2[j + 192], u2 * u2 + red[8][j]);
  }
}

// ---------------------------------------------------------------------------
// K2: gse -> MLP -> sigmoid excite, ONCE in a single block; fold excite + LN
// stats into per-(b,c) scaleA and per-c biasB.
// ---------------------------------------------------------------------------
__global__ __launch_bounds__(288) void k_excite(
    const float* __restrict__ sumS2, const float* __restrict__ sumU,
    const float* __restrict__ sumU2, const float* __restrict__ w1,
    const float* __restrict__ w2, const float* __restrict__ gamma,
    const float* __restrict__ beta, float* __restrict__ scaleA,
    float* __restrict__ biasB) {
  __shared__ float gse[Bk * Ck];
  __shared__ float hid[Bk * 18];
  int t = threadIdx.x;
  for (int i = t; i < Bk * Ck; i += 288) gse[i] = sumS2[i] * (1.f / 65536.f);
  __syncthreads();
  if (t < Bk * 18) {
    int b = t / 18, h = t % 18;
    float s = 0.f;
    for (int c = 0; c < Ck; ++c) s += gse[b * Ck + c] * w1[h * Ck + c];
    hid[t] = s > 0.f ? s : 0.f;
  }
  __syncthreads();
  if (t < Ck) {
    int c = t;
    float m = 0.f, m2 = 0.f;
    float eb[Bk];
    #pragma unroll
    for (int b = 0; b < Bk; ++b) {
      float s = 0.f;
      #pragma unroll
      for (int h = 0; h < 18; ++h) s += hid[b * 18 + h] * w2[c * 18 + h];
      float e = 1.f / (1.f + expf(-s));
      eb[b] = e;
      m  += e * sumU[b * Ck + c];
      m2 += e * e * sumU2[b * Ck + c];
    }
    float mean = m * (1.f / 8192.f);
    float ex2  = m2 * (1.f / 8192.f);
    float var  = ex2 - mean * mean;
    float rsig = rsqrtf(var + 1e-5f);
    float gc = gamma[c];
    #pragma unroll
    for (int b = 0; b < Bk; ++b) scaleA[b * Ck + c] = gc * rsig * eb[b];
    biasB[c] = beta[c] - gc * rsig * mean;
  }
}

// ---------------------------------------------------------------------------
// K3: finalize. Tiled transpose U [B,N1,C] bf16 -> out [B,C,N1] fp32 with
// out = relu(scaleA * u + biasB).
// ---------------------------------------------------------------------------
__global__ void k_finalize(const bf16* __restrict__ U, const float* __restrict__ scaleA,
                           const float* __restrict__ biasB, float* __restrict__ out) {
  __shared__ float tile[32][33];
  int b  = blockIdx.z;
  int cT = blockIdx.y * 32, nT = blockIdx.x * 32;
  int tx = threadIdx.x, ty = threadIdx.y;  // 32 x 8
  const bf16* Ub = U + (size_t)b * N1k * Ck;
  #pragma unroll
  for (int j = 0; j < 32; j += 8)
    tile[ty + j][tx] = __bfloat162float(Ub[(size_t)(nT + ty + j) * Ck + cT + tx]);
  __syncthreads();
  float* Ob = out + (size_t)b * Ck * N1k;
  #pragma unroll
  for (int j = 0; j < 32; j += 8) {
    int c = cT + ty + j;
    float v = scaleA[b * Ck + c] * tile[tx][ty + j] + biasB[c];
    Ob[(size_t)c * N1k + nT + tx] = v > 0.f ? v : 0.f;
  }
}

// ---------------------------------------------------------------------------
extern "C" void kernel_launch(void* const* d_in, const int* in_sizes, int n_in,
                              void* d_out, int out_size, void* d_ws, size_t ws_size,
                              hipStream_t stream) {
  const float* qxyz  = (const float*)d_in[0];
  const float* sxyz  = (const float*)d_in[1];
  const float* qm    = (const float*)d_in[2];
  const float* sm    = (const float*)d_in[3];
  const float* F     = (const float*)d_in[4];
  const float* w1    = (const float*)d_in[5];
  const float* w2    = (const float*)d_in[6];
  const float* gamma = (const float*)d_in[7];
  const float* beta  = (const float*)d_in[8];

  char* ws = (char*)d_ws;
  size_t off = 0;
  auto alloc = [&](size_t bytes) {
    off = (off + 255) & ~(size_t)255;
    void* p = ws + off;
    off += bytes;
    return p;
  };
  bf16*  Ftr    = (bf16*) alloc(sizeof(bf16)  * (size_t)Bk * N2k * Ck);
  bf16*  U      = (bf16*) alloc(sizeof(bf16)  * (size_t)Bk * N1k * Ck);
  int*   idxArr = (int*)  alloc(sizeof(int)   * (size_t)Bk * N1k * NSk);
  int*   cntArr = (int*)  alloc(sizeof(int)   * (size_t)Bk * N1k);
  float* sums   = (float*)alloc(sizeof(float) * 3 * Bk * Ck);
  float* sumS2 = sums;
  float* sumU  = sums + Bk * Ck;
  float* sumU2 = sums + 2 * Bk * Ck;
  float* scaleA = (float*)alloc(sizeof(float) * Bk * Ck);
  float* biasB  = (float*)alloc(sizeof(float) * Ck);

  k_pre<<<TRB + Bk * (N1k / 4), 256, 0, stream>>>(F, sxyz, sm, qxyz, qm, Ftr,
                                                  idxArr, cntArr, sums);
  k_aggregate<<<Bk * (N1k / 2), 192, 0, stream>>>(Ftr, qxyz, sxyz, qm, idxArr, cntArr,
                                                  U, sumS2, sumU, sumU2);
  k_excite<<<1, 288, 0, stream>>>(sumS2, sumU, sumU2, w1, w2, gamma, beta, scaleA, biasB);
  k_finalize<<<dim3(N1k / 32, Ck / 32, Bk), dim3(32, 8), 0, stream>>>(U, scaleA, biasB,
                                                                      (float*)d_out);
}

// Round 12
// 69.354 us; speedup vs baseline: 2.9885x; 1.1255x over previous
//
#include <hip/hip_runtime.h>
#include <hip/hip_bf16.h>
#include <cstdint>
#include <cstddef>

static constexpr int Bk  = 4;
static constexpr int N1k = 2048;
static constexpr int N2k = 8192;
static constexpr int Ck  = 288;
static constexpr int NSk = 32;
static constexpr int TRB = (N2k / 32) * (Ck / 32) * Bk;   // 9216 transpose blocks

typedef __hip_bfloat16 bf16;

// ---------------------------------------------------------------------------
// K0 (heterogeneous grid): blocks [0,TRB) transpose support_features
// [B,C,N2] fp32 -> Ftr [B,N2,C] bf16 (+ block 0 zeroes sums); blocks
// [TRB, TRB+2048) run the masked ball query (wave per query, 4 pts/lane/iter
// with scalar prefetch). Transpose FIRST (the HBM stream k_aggregate waits
// on); BQ tail waves overlap the stream.   [R7-proven configuration]
// ---------------------------------------------------------------------------
__global__ __launch_bounds__(256) void k_pre(
    const float* __restrict__ F, const float* __restrict__ sxyz,
    const float* __restrict__ smask, const float* __restrict__ qxyz,
    const float* __restrict__ qmask, bf16* __restrict__ Ftr,
    int* __restrict__ idxArr, int* __restrict__ cntArr,
    float* __restrict__ sums) {
  __shared__ float tile[32][33];
  int t = threadIdx.x;

  if (blockIdx.x < TRB) {
    // ---- transpose part ----
    int i  = blockIdx.x;
    int sT = (i & 255) * 32;
    int yz = i >> 8;
    int cT = (yz % 9) * 32;
    int b  = yz / 9;
    int tx = t & 31, ty = t >> 5;      // 32 x 8
    const float* Fb = F + (size_t)b * Ck * N2k;
    #pragma unroll
    for (int j = 0; j < 32; j += 8)
      tile[ty + j][tx] = Fb[(size_t)(cT + ty + j) * N2k + sT + tx];
    if (i == 0) {
      for (int k = t; k < 3 * Bk * Ck; k += 256) sums[k] = 0.f;
    }
    __syncthreads();
    bf16* Ob = Ftr + (size_t)b * N2k * Ck;
    #pragma unroll
    for (int j = 0; j < 32; j += 8)
      Ob[(size_t)(sT + ty + j) * Ck + cT + tx] = __float2bfloat16(tile[tx][ty + j]);
    return;
  }

  // ---- ball query part ----
  int wave = (blockIdx.x - TRB) * 4 + (t >> 6);
  int lane = t & 63;
  int b = wave >> 11;                  // N1k = 2048
  int n = wave & (N1k - 1);
  int q = b * N1k + n;
  float qm = qmask[q];
  float qx = qxyz[q * 3 + 0];
  float qy = qxyz[q * 3 + 1];
  float qz = qxyz[q * 3 + 2];
  int cnt = 0, firstIdx = 0;
  int* myIdx = idxArr + (size_t)q * NSk;
  const float* Sx = sxyz + (size_t)b * N2k * 3;
  const float* Sm = smask + (size_t)b * N2k;
  if (qm > 0.f) {
    unsigned long long lmlt = (1ull << lane) - 1ull;
    float cx[4], cy[4], cz[4], cm[4];
    #pragma unroll
    for (int u = 0; u < 4; ++u) {
      int s = u * 64 + lane;
      cx[u] = Sx[3 * s]; cy[u] = Sx[3 * s + 1]; cz[u] = Sx[3 * s + 2];
      cm[u] = Sm[s];
    }
    for (int s0 = 0; s0 < N2k && cnt < NSk; s0 += 256) {
      float nx[4], ny[4], nz[4], nm[4];
      #pragma unroll
      for (int u = 0; u < 4; ++u) {
        int sp = s0 + 256 + u * 64 + lane;
        sp = (sp < N2k) ? sp : 0;      // clamped, unconditional prefetch
        nx[u] = Sx[3 * sp]; ny[u] = Sx[3 * sp + 1]; nz[u] = Sx[3 * sp + 2];
        nm[u] = Sm[sp];
      }
      #pragma unroll
      for (int u = 0; u < 4; ++u) {
        float dx = qx - cx[u], dy = qy - cy[u], dz = qz - cz[u];
        // match numpy association: (dx^2 + dy^2) + dz^2, no FMA contraction
        float d2 = __fadd_rn(__fadd_rn(__fmul_rn(dx, dx), __fmul_rn(dy, dy)),
                             __fmul_rn(dz, dz));
        bool valid = (d2 < 0.04f) && (cm[u] > 0.f);
        unsigned long long m = __ballot(valid);
        if (cnt == 0 && m != 0ull) firstIdx = s0 + u * 64 + (int)__builtin_ctzll(m);
        int p = cnt + (int)__popcll(m & lmlt);
        if (valid && p < NSk) myIdx[p] = s0 + u * 64 + lane;
        cnt += (int)__popcll(m);
      }
      #pragma unroll
      for (int u = 0; u < 4; ++u) {
        cx[u] = nx[u]; cy[u] = ny[u]; cz[u] = nz[u]; cm[u] = nm[u];
      }
    }
    if (cnt > NSk) cnt = NSk;
  }
  for (int p = cnt + lane; p < NSk; p += 64) myIdx[p] = firstIdx;
  if (lane == 0) cntArr[q] = cnt;
}

// ---------------------------------------------------------------------------
// K1: main aggregation (R7/R4-proven). Block = 192 threads = 2 groups x 96;
// each group handles one query per "it"; 2 its -> 4 queries/block -> 2048
// blocks. b = blockIdx&3 pins XCDs (round-robin dispatch) to one batch's
// Ftr slice. Thread j of a group owns channels {j, j+96, j+192} (rel axis
// j%3), 3 independent 2B loads per k, unroll 8 (~24 loads in flight).
//  a2[c] = sum_k F[idx_k][c] * rel[k][c%3]                (unmasked, for gse)
//  a1[c] = sum_k F[idx_k][c] * rel[k][c%3] * fm[k]        (masked)
//  U[b,n,c] = a1 / sum_k fm[k]   (stored bf16)
// Per-(b,c) sums (gse, sumU, sumU2) via cross-group LDS merge + atomics.
// ---------------------------------------------------------------------------
__global__ __launch_bounds__(192, 6) void k_aggregate(
    const bf16* __restrict__ Ftr, const float* __restrict__ qxyz,
    const float* __restrict__ sxyz, const float* __restrict__ qmask,
    const int* __restrict__ idxArr, const int* __restrict__ cntArr,
    bf16* __restrict__ U, float* __restrict__ sumS2,
    float* __restrict__ sumU, float* __restrict__ sumU2) {
  __shared__ int   sidx[2][NSk];
  __shared__ float srel[2][NSk][3];
  __shared__ float srelm[2][NSk][3];
  __shared__ float sfinv[2];
  __shared__ float red[9][96];

  int b     = blockIdx.x & 3;
  int nbase = (blockIdx.x >> 2) * 4;    // 512 blocks per batch, 4 queries each
  int g = threadIdx.x / 96;
  int j = threadIdx.x % 96;
  int a = j % 3;

  float sS2[3]  = {0.f, 0.f, 0.f};
  float sUa[3]  = {0.f, 0.f, 0.f};
  float sU2a[3] = {0.f, 0.f, 0.f};

  const bf16* Fb = Ftr + (size_t)b * N2k * Ck;

  for (int it = 0; it < 2; ++it) {
    int n = nbase + it * 2 + g;
    int q = b * N1k + n;
    __syncthreads();
    if (j < NSk) {
      int k = j;
      int i = idxArr[(size_t)q * NSk + k];
      sidx[g][k] = i;
      float qx = qxyz[q * 3 + 0], qy = qxyz[q * 3 + 1], qz = qxyz[q * 3 + 2];
      float sx = sxyz[(b * N2k + i) * 3 + 0];
      float sy = sxyz[(b * N2k + i) * 3 + 1];
      float sz = sxyz[(b * N2k + i) * 3 + 2];
      float rx = (sx - qx) / 0.2f;
      float ry = (sy - qy) / 0.2f;
      float rz = (sz - qz) / 0.2f;
      float qmv = qmask[q];
      int fnd = cntArr[q];
      float fmk = (qmv > 0.f) ? ((k < fnd) ? 1.f : 0.f) : 1.f;
      srel[g][k][0] = rx; srel[g][k][1] = ry; srel[g][k][2] = rz;
      srelm[g][k][0] = rx * fmk; srelm[g][k][1] = ry * fmk; srelm[g][k][2] = rz * fmk;
      if (k == 0) {
        float fmsum = (qmv > 0.f) ? (float)fnd : (float)NSk;
        sfinv[g] = (fmsum > 0.f) ? (1.f / fmsum) : 0.f;
      }
    }
    __syncthreads();

    float a1[3] = {0.f, 0.f, 0.f};
    float a2[3] = {0.f, 0.f, 0.f};
    #pragma unroll 8
    for (int k = 0; k < NSk; ++k) {
      const bf16* row = Fb + (size_t)sidx[g][k] * Ck;
      float f0 = __bfloat162float(row[j]);
      float f1 = __bfloat162float(row[j + 96]);
      float f2 = __bfloat162float(row[j + 192]);
      float r  = srel[g][k][a];
      float rm = srelm[g][k][a];
      a2[0] = fmaf(f0, r, a2[0]);
      a2[1] = fmaf(f1, r, a2[1]);
      a2[2] = fmaf(f2, r, a2[2]);
      a1[0] = fmaf(f0, rm, a1[0]);
      a1[1] = fmaf(f1, rm, a1[1]);
      a1[2] = fmaf(f2, rm, a1[2]);
    }
    float finv = sfinv[g];
    float u0 = a1[0] * finv, u1 = a1[1] * finv, u2 = a1[2] * finv;
    bf16* Urow = U + (size_t)q * Ck;
    Urow[j]       = __float2bfloat16(u0);
    Urow[j + 96]  = __float2bfloat16(u1);
    Urow[j + 192] = __float2bfloat16(u2);
    sS2[0] += a2[0]; sS2[1] += a2[1]; sS2[2] += a2[2];
    sUa[0] += u0;    sUa[1] += u1;    sUa[2] += u2;
    sU2a[0] += u0 * u0; sU2a[1] += u1 * u1; sU2a[2] += u2 * u2;
  }

  // cross-group merge in LDS, then one set of atomics from group 0
  __syncthreads();
  if (g == 1) {
    red[0][j] = sS2[0];  red[1][j] = sS2[1];  red[2][j] = sS2[2];
    red[3][j] = sUa[0];  red[4][j] = sUa[1];  red[5][j] = sUa[2];
    red[6][j] = sU2a[0]; red[7][j] = sU2a[1]; red[8][j] = sU2a[2];
  }
  __syncthreads();
  if (g == 0) {
    float* pS2 = sumS2 + b * Ck;
    float* pU  = sumU  + b * Ck;
    float* pU2 = sumU2 + b * Ck;
    atomicAdd(&pS2[j],       sS2[0]  + red[0][j]);
    atomicAdd(&pS2[j + 96],  sS2[1]  + red[1][j]);
    atomicAdd(&pS2[j + 192], sS2[2]  + red[2][j]);
    atomicAdd(&pU[j],        sUa[0]  + red[3][j]);
    atomicAdd(&pU[j + 96],   sUa[1]  + red[4][j]);
    atomicAdd(&pU[j + 192],  sUa[2]  + red[5][j]);
    atomicAdd(&pU2[j],       sU2a[0] + red[6][j]);
    atomicAdd(&pU2[j + 96],  sU2a[1] + red[7][j]);
    atomicAdd(&pU2[j + 192], sU2a[2] + red[8][j]);
  }
}

// ---------------------------------------------------------------------------
// K2: gse -> MLP -> sigmoid excite, ONCE in a single block; fold excite + LN
// stats into per-(b,c) scaleA and per-c biasB.
// ---------------------------------------------------------------------------
__global__ __launch_bounds__(288) void k_excite(
    const float* __restrict__ sumS2, const float* __restrict__ sumU,
    const float* __restrict__ sumU2, const float* __restrict__ w1,
    const float* __restrict__ w2, const float* __restrict__ gamma,
    const float* __restrict__ beta, float* __restrict__ scaleA,
    float* __restrict__ biasB) {
  __shared__ float gse[Bk * Ck];
  __shared__ float hid[Bk * 18];
  int t = threadIdx.x;
  for (int i = t; i < Bk * Ck; i += 288) gse[i] = sumS2[i] * (1.f / 65536.f);
  __syncthreads();
  if (t < Bk * 18) {
    int b = t / 18, h = t % 18;
    float s = 0.f;
    for (int c = 0; c < Ck; ++c) s += gse[b * Ck + c] * w1[h * Ck + c];
    hid[t] = s > 0.f ? s : 0.f;
  }
  __syncthreads();
  if (t < Ck) {
    int c = t;
    float m = 0.f, m2 = 0.f;
    float eb[Bk];
    #pragma unroll
    for (int b = 0; b < Bk; ++b) {
      float s = 0.f;
      #pragma unroll
      for (int h = 0; h < 18; ++h) s += hid[b * 18 + h] * w2[c * 18 + h];
      float e = 1.f / (1.f + expf(-s));
      eb[b] = e;
      m  += e * sumU[b * Ck + c];
      m2 += e * e * sumU2[b * Ck + c];
    }
    float mean = m * (1.f / 8192.f);
    float ex2  = m2 * (1.f / 8192.f);
    float var  = ex2 - mean * mean;
    float rsig = rsqrtf(var + 1e-5f);
    float gc = gamma[c];
    #pragma unroll
    for (int b = 0; b < Bk; ++b) scaleA[b * Ck + c] = gc * rsig * eb[b];
    biasB[c] = beta[c] - gc * rsig * mean;
  }
}

// ---------------------------------------------------------------------------
// K3: finalize. Tiled transpose U [B,N1,C] bf16 -> out [B,C,N1] fp32 with
// out = relu(scaleA * u + biasB).
// ---------------------------------------------------------------------------
__global__ void k_finalize(const bf16* __restrict__ U, const float* __restrict__ scaleA,
                           const float* __restrict__ biasB, float* __restrict__ out) {
  __shared__ float tile[32][33];
  int b  = blockIdx.z;
  int cT = blockIdx.y * 32, nT = blockIdx.x * 32;
  int tx = threadIdx.x, ty = threadIdx.y;  // 32 x 8
  const bf16* Ub = U + (size_t)b * N1k * Ck;
  #pragma unroll
  for (int j = 0; j < 32; j += 8)
    tile[ty + j][tx] = __bfloat162float(Ub[(size_t)(nT + ty + j) * Ck + cT + tx]);
  __syncthreads();
  float* Ob = out + (size_t)b * Ck * N1k;
  #pragma unroll
  for (int j = 0; j < 32; j += 8) {
    int c = cT + ty + j;
    float v = scaleA[b * Ck + c] * tile[tx][ty + j] + biasB[c];
    Ob[(size_t)c * N1k + nT + tx] = v > 0.f ? v : 0.f;
  }
}

// ---------------------------------------------------------------------------
extern "C" void kernel_launch(void* const* d_in, const int* in_sizes, int n_in,
                              void* d_out, int out_size, void* d_ws, size_t ws_size,
                              hipStream_t stream) {
  const float* qxyz  = (const float*)d_in[0];
  const float* sxyz  = (const float*)d_in[1];
  const float* qm    = (const float*)d_in[2];
  const float* sm    = (const float*)d_in[3];
  const float* F     = (const float*)d_in[4];
  const float* w1    = (const float*)d_in[5];
  const float* w2    = (const float*)d_in[6];
  const float* gamma = (const float*)d_in[7];
  const float* beta  = (const float*)d_in[8];

  char* ws = (char*)d_ws;
  size_t off = 0;
  auto alloc = [&](size_t bytes) {
    off = (off + 255) & ~(size_t)255;
    void* p = ws + off;
    off += bytes;
    return p;
  };
  bf16*  Ftr    = (bf16*) alloc(sizeof(bf16)  * (size_t)Bk * N2k * Ck);
  bf16*  U      = (bf16*) alloc(sizeof(bf16)  * (size_t)Bk * N1k * Ck);
  int*   idxArr = (int*)  alloc(sizeof(int)   * (size_t)Bk * N1k * NSk);
  int*   cntArr = (int*)  alloc(sizeof(int)   * (size_t)Bk * N1k);
  float* sums   = (float*)alloc(sizeof(float) * 3 * Bk * Ck);
  float* sumS2 = sums;
  float* sumU  = sums + Bk * Ck;
  float* sumU2 = sums + 2 * Bk * Ck;
  float* scaleA = (float*)alloc(sizeof(float) * Bk * Ck);
  float* biasB  = (float*)alloc(sizeof(float) * Ck);

  k_pre<<<TRB + Bk * (N1k / 4), 256, 0, stream>>>(F, sxyz, sm, qxyz, qm, Ftr,
                                                  idxArr, cntArr, sums);
  k_aggregate<<<Bk * (N1k / 4), 192, 0, stream>>>(Ftr, qxyz, sxyz, qm, idxArr, cntArr,
                                                  U, sumS2, sumU, sumU2);
  k_excite<<<1, 288, 0, stream>>>(sumS2, sumU, sumU2, w1, w2, gamma, beta, scaleA, biasB);
  k_finalize<<<dim3(N1k / 32, Ck / 32, Bk), dim3(32, 8), 0, stream>>>(U, scaleA, biasB,
                                                                      (float*)d_out);
}